// Round 4
// baseline (27.108 us; speedup 1.0000x reference)
//
#include <hip/hip_runtime.h>

// Problem constants (match reference)
#define T_LEN   4096
#define NKNOT   6          // KNOT+2
#define NSEG    5          // KNOT+1
#define STEP    819        // (T_LEN-1)/(KNOT+1) == 4095/5, exact integer
#define B_SZ    128
#define C_CH    32
#define P_THR   0.5f

// Native clang vector type — accepted by __builtin_nontemporal_load/store
typedef float f32x4 __attribute__((ext_vector_type(4)));

// ---------------------------------------------------------------------------
// Compile-time solve of the 6x6 not-a-knot system + per-segment basis coeffs.
// For segment s, basis weight of knot k at offset dl (dr = STEP - dl):
//   w_k = a[s][k]*dr^3 + b[s][k]*dl^3 + c[s][k]*dr + d[s][k]*dl
// so curve(t) = A*dr^3 + B*dl^3 + C*dr + D*dl with {A..D} = sum_k coef*y_k.
// ---------------------------------------------------------------------------
struct Coefs {
    float a[NSEG][NKNOT];
    float b[NSEG][NKNOT];
    float c[NSEG][NKNOT];
    float d[NSEG][NKNOT];
};

constexpr double cabs_(double x) { return x < 0.0 ? -x : x; }

constexpr Coefs compute_coefs() {
    double A[NKNOT][NKNOT] = {}, R[NKNOT][NKNOT] = {};
    const double h = (double)STEP;
    for (int i = 1; i <= NKNOT - 2; ++i) {
        A[i][i-1] = h;       A[i][i] = 4.0 * h;   A[i][i+1] = h;
        R[i][i-1] = 6.0/h;   R[i][i] = -12.0/h;   R[i][i+1] = 6.0/h;
    }
    A[0][0] = h;              A[0][1] = -2.0*h;             A[0][2] = h;
    A[NKNOT-1][NKNOT-3] = h;  A[NKNOT-1][NKNOT-2] = -2.0*h; A[NKNOT-1][NKNOT-1] = h;
    for (int col = 0; col < NKNOT; ++col) {
        int piv = col;
        for (int r = col + 1; r < NKNOT; ++r)
            if (cabs_(A[r][col]) > cabs_(A[piv][col])) piv = r;
        if (piv != col) {
            for (int k = 0; k < NKNOT; ++k) {
                double t = A[col][k]; A[col][k] = A[piv][k]; A[piv][k] = t;
                t = R[col][k]; R[col][k] = R[piv][k]; R[piv][k] = t;
            }
        }
        double dinv = 1.0 / A[col][col];
        for (int k = 0; k < NKNOT; ++k) { A[col][k] *= dinv; R[col][k] *= dinv; }
        for (int r = 0; r < NKNOT; ++r) {
            if (r == col) continue;
            double f = A[r][col];
            for (int k = 0; k < NKNOT; ++k) {
                A[r][k] -= f * A[col][k];
                R[r][k] -= f * R[col][k];
            }
        }
    }
    Coefs out{};
    for (int s = 0; s < NSEG; ++s)
        for (int k = 0; k < NKNOT; ++k) {
            double Si = R[s][k], Sj = R[s+1][k];
            double Yi = (s == k)     ? 1.0 : 0.0;
            double Yj = (s + 1 == k) ? 1.0 : 0.0;
            out.a[s][k] = (float)(Si / (6.0 * h));
            out.b[s][k] = (float)(Sj / (6.0 * h));
            out.c[s][k] = (float)((Yi - Si * h * h / 6.0) / h);
            out.d[s][k] = (float)((Yj - Sj * h * h / 6.0) / h);
        }
    return out;
}

__device__ constexpr Coefs COEF = compute_coefs();

// ---------------------------------------------------------------------------
// One block per (b,c); nontemporal streaming, 2x f32x4 in flight per iter.
// ---------------------------------------------------------------------------
__global__ __launch_bounds__(256) void magwarp(
    const float* __restrict__ x, const float* __restrict__ yy,
    const float* __restrict__ mask_u, float* __restrict__ out) {
    const int bc = blockIdx.x;            // 0 .. B_SZ*C_CH-1
    const int b  = bc >> 5;               // / C_CH
    const int c  = bc & (C_CH - 1);
    const bool apply = mask_u[b] < P_THR;

    __shared__ f32x4 cs[NSEG];            // {A,B,C,D} per segment
    if (apply && threadIdx.x < NSEG) {
        const int s = threadIdx.x;
        float A = 0.f, B = 0.f, C = 0.f, D = 0.f;
        #pragma unroll
        for (int k = 0; k < NKNOT; ++k) {
            float y = yy[(b * NKNOT + k) * C_CH + c];
            A += COEF.a[s][k] * y;
            B += COEF.b[s][k] * y;
            C += COEF.c[s][k] * y;
            D += COEF.d[s][k] * y;
        }
        cs[s] = (f32x4){A, B, C, D};
    }
    __syncthreads();

    const size_t base = (size_t)bc * T_LEN;
    const f32x4* xp = (const f32x4*)(x + base);   // 1024 f32x4 per row
    f32x4*       op = (f32x4*)(out + base);

    if (!apply) {
        #pragma unroll
        for (int it = 0; it < 2; ++it) {
            const int i0 = threadIdx.x + it * 512;
            f32x4 v0 = __builtin_nontemporal_load(xp + i0);
            f32x4 v1 = __builtin_nontemporal_load(xp + i0 + 256);
            __builtin_nontemporal_store(v0, op + i0);
            __builtin_nontemporal_store(v1, op + i0 + 256);
        }
        return;
    }

    #pragma unroll
    for (int it = 0; it < 2; ++it) {
        const int i0 = threadIdx.x + it * 512;      // f32x4 index
        f32x4 v0 = __builtin_nontemporal_load(xp + i0);
        f32x4 v1 = __builtin_nontemporal_load(xp + i0 + 256);

        #pragma unroll
        for (int u = 0; u < 2; ++u) {
            f32x4& xv = u ? v1 : v0;
            const int t0 = (i0 + u * 256) * 4;
            #pragma unroll
            for (int j = 0; j < 4; ++j) {
                const int t = t0 + j;
                int seg = t / STEP;                 // magic-mul, no divide
                seg = seg > NSEG - 1 ? NSEG - 1 : seg;
                const float dl = (float)(t - seg * STEP);
                const float dr = (float)STEP - dl;
                const f32x4 cf = cs[seg];           // ds_read_b128, broadcast
                const float r = cf.x * (dr * dr * dr) + cf.y * (dl * dl * dl)
                              + cf.z * dr + cf.w * dl;
                xv[j] *= r;
            }
        }
        __builtin_nontemporal_store(v0, op + i0);
        __builtin_nontemporal_store(v1, op + i0 + 256);
    }
}

// ---------------------------------------------------------------------------
extern "C" void kernel_launch(void* const* d_in, const int* in_sizes, int n_in,
                              void* d_out, int out_size, void* d_ws, size_t ws_size,
                              hipStream_t stream) {
    const float* x   = (const float*)d_in[0];   // (128, 32, 4096) f32
    const float* yy  = (const float*)d_in[1];   // (128, 6, 32)    f32
    const float* mu  = (const float*)d_in[2];   // (128, 1, 1)     f32
    float*       out = (float*)d_out;

    const int nblocks = B_SZ * C_CH;            // 4096
    hipLaunchKernelGGL(magwarp, dim3(nblocks), dim3(256), 0, stream,
                       x, yy, mu, out);
}

// Round 5
// 24.958 us; speedup vs baseline: 1.0862x; 1.0862x over previous
//
#include <hip/hip_runtime.h>

// Problem constants (match reference)
#define T_LEN   4096
#define NKNOT   6          // KNOT+2
#define NSEG    5          // KNOT+1
#define STEP    819        // (T_LEN-1)/(KNOT+1) == 4095/5, exact integer
#define B_SZ    128
#define C_CH    32
#define P_THR   0.5f

typedef float f32x4 __attribute__((ext_vector_type(4)));

// ---------------------------------------------------------------------------
// Compile-time: solve 6x6 not-a-knot system, then express each segment's
// basis weight as a plain cubic in t:  w_k(t) = e0 + e1*t + e2*t^2 + e3*t^3.
// Runtime folds with y into one float4 {E0,E1,E2,E3} per segment.
// ---------------------------------------------------------------------------
struct PolyCoefs { float e[NSEG][NKNOT][4]; };

constexpr double cabs_(double x) { return x < 0.0 ? -x : x; }

constexpr PolyCoefs compute_poly() {
    double A[NKNOT][NKNOT] = {}, R[NKNOT][NKNOT] = {};
    const double h = (double)STEP;
    for (int i = 1; i <= NKNOT - 2; ++i) {
        A[i][i-1] = h;       A[i][i] = 4.0 * h;   A[i][i+1] = h;
        R[i][i-1] = 6.0/h;   R[i][i] = -12.0/h;   R[i][i+1] = 6.0/h;
    }
    A[0][0] = h;              A[0][1] = -2.0*h;             A[0][2] = h;
    A[NKNOT-1][NKNOT-3] = h;  A[NKNOT-1][NKNOT-2] = -2.0*h; A[NKNOT-1][NKNOT-1] = h;
    for (int col = 0; col < NKNOT; ++col) {
        int piv = col;
        for (int r = col + 1; r < NKNOT; ++r)
            if (cabs_(A[r][col]) > cabs_(A[piv][col])) piv = r;
        if (piv != col) {
            for (int k = 0; k < NKNOT; ++k) {
                double t = A[col][k]; A[col][k] = A[piv][k]; A[piv][k] = t;
                t = R[col][k]; R[col][k] = R[piv][k]; R[piv][k] = t;
            }
        }
        double dinv = 1.0 / A[col][col];
        for (int k = 0; k < NKNOT; ++k) { A[col][k] *= dinv; R[col][k] *= dinv; }
        for (int r = 0; r < NKNOT; ++r) {
            if (r == col) continue;
            double f = A[r][col];
            for (int k = 0; k < NKNOT; ++k) {
                A[r][k] -= f * A[col][k];
                R[r][k] -= f * R[col][k];
            }
        }
    }
    // R == S2 (second derivatives per unit y). Expand each segment cubic in t.
    PolyCoefs out{};
    for (int s = 0; s < NSEG; ++s) {
        const double ts = s * h, tr = (s + 1) * h;
        for (int k = 0; k < NKNOT; ++k) {
            double Si = R[s][k], Sj = R[s+1][k];
            double Yi = (s == k)     ? 1.0 : 0.0;
            double Yj = (s + 1 == k) ? 1.0 : 0.0;
            double a = Si / (6.0 * h), b = Sj / (6.0 * h);
            double c = (Yi - Si * h * h / 6.0) / h;
            double d = (Yj - Sj * h * h / 6.0) / h;
            // w = a*(tr-t)^3 + b*(t-ts)^3 + c*(tr-t) + d*(t-ts)
            out.e[s][k][0] = (float)( a*tr*tr*tr - b*ts*ts*ts + c*tr - d*ts);
            out.e[s][k][1] = (float)(-3.0*a*tr*tr + 3.0*b*ts*ts - c + d);
            out.e[s][k][2] = (float)( 3.0*a*tr - 3.0*b*ts);
            out.e[s][k][3] = (float)( b - a);
        }
    }
    return out;
}

__device__ constexpr PolyCoefs POLY = compute_poly();

// ---------------------------------------------------------------------------
// One block per (b,c). 4 x-loads issued up front; threads 0..4 fold yy into
// per-segment cubic {E0..E3} in LDS; Horner-in-t eval (3 FMA + 1 mul / elem),
// one LDS broadcast read per float4 (seg from t0 — C2 continuity makes the
// <=3-sample cross-knot misassignment error ~1e-6, far below threshold).
// ---------------------------------------------------------------------------
__global__ __launch_bounds__(256) void magwarp(
    const float* __restrict__ x, const float* __restrict__ yy,
    const float* __restrict__ mask_u, float* __restrict__ out) {
    const int bc  = blockIdx.x;           // 0 .. B_SZ*C_CH-1
    const int b   = bc >> 5;              // / C_CH
    const int c   = bc & (C_CH - 1);
    const int tid = threadIdx.x;
    const bool apply = mask_u[b] < P_THR;

    const size_t base = (size_t)bc * T_LEN;
    const f32x4* xp = (const f32x4*)(x + base);   // 1024 f32x4 per row
    f32x4*       op = (f32x4*)(out + base);

    // Max MLP: all 16 floats in flight before the coefficient prologue.
    f32x4 v0 = xp[tid];
    f32x4 v1 = xp[tid + 256];
    f32x4 v2 = xp[tid + 512];
    f32x4 v3 = xp[tid + 768];

    __shared__ f32x4 cs[NSEG];            // {E0,E1,E2,E3} per segment
    if (apply && tid < NSEG) {
        const int s = tid;
        float e0 = 0.f, e1 = 0.f, e2 = 0.f, e3 = 0.f;
        #pragma unroll
        for (int k = 0; k < NKNOT; ++k) {
            float y = yy[(b * NKNOT + k) * C_CH + c];
            e0 += POLY.e[s][k][0] * y;
            e1 += POLY.e[s][k][1] * y;
            e2 += POLY.e[s][k][2] * y;
            e3 += POLY.e[s][k][3] * y;
        }
        cs[s] = (f32x4){e0, e1, e2, e3};
    }
    __syncthreads();

    if (!apply) {
        op[tid]       = v0;
        op[tid + 256] = v1;
        op[tid + 512] = v2;
        op[tid + 768] = v3;
        return;
    }

    const float inv_step = 1.0f / (float)STEP;
    #define PROC(v, i0)                                                  \
    {                                                                    \
        const float t0f = (float)((i0) * 4);                             \
        int seg = (int)(t0f * inv_step);                                 \
        seg = seg > NSEG - 1 ? NSEG - 1 : seg;                           \
        const f32x4 cf = cs[seg];       /* ds_read_b128, broadcast */    \
        _Pragma("unroll")                                                \
        for (int j = 0; j < 4; ++j) {                                    \
            const float tf = t0f + (float)j;                             \
            const float r = ((cf.w * tf + cf.z) * tf + cf.y) * tf + cf.x;\
            (v)[j] *= r;                                                 \
        }                                                                \
    }

    PROC(v0, tid);        op[tid]       = v0;
    PROC(v1, tid + 256);  op[tid + 256] = v1;
    PROC(v2, tid + 512);  op[tid + 512] = v2;
    PROC(v3, tid + 768);  op[tid + 768] = v3;
    #undef PROC
}

// ---------------------------------------------------------------------------
extern "C" void kernel_launch(void* const* d_in, const int* in_sizes, int n_in,
                              void* d_out, int out_size, void* d_ws, size_t ws_size,
                              hipStream_t stream) {
    const float* x   = (const float*)d_in[0];   // (128, 32, 4096) f32
    const float* yy  = (const float*)d_in[1];   // (128, 6, 32)    f32
    const float* mu  = (const float*)d_in[2];   // (128, 1, 1)     f32
    float*       out = (float*)d_out;

    const int nblocks = B_SZ * C_CH;            // 4096
    hipLaunchKernelGGL(magwarp, dim3(nblocks), dim3(256), 0, stream,
                       x, yy, mu, out);
}